// Round 4
// baseline (686.107 us; speedup 1.0000x reference)
//
#include <hip/hip_runtime.h>
#include <hip/hip_bf16.h>
#include <math.h>

#define NFM 512   // NFMODES
#define NE  256
#define NUN 32    // NUNPAIRED
#define NM  480   // NMODES
#define NB  32    // BATCH
#define NF  288   // NE + NUN  (Ffull dim)
#define WP  16    // panel width
#define PAIRS 8   // WP/2
#define PP  17    // panel LDS pitch
#define NW  5     // ceil(NF/64) row slots per lane

typedef unsigned long long ull;

#define LGKM0() asm volatile("s_waitcnt lgkmcnt(0)" ::: "memory")
#define VM0()   asm volatile("s_waitcnt vmcnt(0)" ::: "memory")

// ---------------- Ja = (J - J^T)/2 ----------------
__global__ __launch_bounds__(256)
void build_ja_k(const float* __restrict__ J, float* __restrict__ Ja) {
  int t = blockIdx.x * blockDim.x + threadIdx.x;
  int stride = gridDim.x * blockDim.x;
  for (int e = t; e < NM * NM; e += stride) {
    int i = e / NM, j = e - i * NM;
    Ja[e] = 0.5f * (J[i * NM + j] - J[j * NM + i]);
  }
}

// ---------------- Tmp[b] (256x480) = Up_b @ Ja ----------
__global__ __launch_bounds__(256)
void gemm1_k(const float* __restrict__ U, const int* __restrict__ idx,
             const float* __restrict__ Ja, float* __restrict__ Tmp) {
  const int b  = blockIdx.z;
  const int m0 = blockIdx.y << 6;
  const int n0 = blockIdx.x << 6;
  const int tid = threadIdx.x;
  __shared__ float As[16][64];
  __shared__ float Bs[16][64];
  const int ar = tid >> 2, ac = (tid & 3) << 2;
  const int br = tid >> 4, bc = (tid & 15) << 2;
  const int tx = tid & 15, ty = tid >> 4;
  const float* Arow = U + (size_t)idx[b * NE + m0 + ar] * NFM + NUN;
  float acc[4][4] = {};
  for (int l0 = 0; l0 < NM; l0 += 16) {
    float4 av = *(const float4*)(Arow + l0 + ac);
    As[ac + 0][ar] = av.x; As[ac + 1][ar] = av.y;
    As[ac + 2][ar] = av.z; As[ac + 3][ar] = av.w;
    float4 bv = make_float4(0.f, 0.f, 0.f, 0.f);
    if (n0 + bc < NM) bv = *(const float4*)(Ja + (size_t)(l0 + br) * NM + n0 + bc);
    *(float4*)(&Bs[br][bc]) = bv;
    __syncthreads();
#pragma unroll
    for (int kk = 0; kk < 16; ++kk) {
      float4 a4 = *(const float4*)(&As[kk][ty << 2]);
      float4 b4 = *(const float4*)(&Bs[kk][tx << 2]);
      float a[4] = {a4.x, a4.y, a4.z, a4.w};
      float bb[4] = {b4.x, b4.y, b4.z, b4.w};
#pragma unroll
      for (int q = 0; q < 4; ++q)
#pragma unroll
        for (int p = 0; p < 4; ++p) acc[q][p] = fmaf(a[q], bb[p], acc[q][p]);
    }
    __syncthreads();
  }
  float* Tb = Tmp + (size_t)b * NE * NM;
#pragma unroll
  for (int q = 0; q < 4; ++q) {
    int r = m0 + (ty << 2) + q;
#pragma unroll
    for (int p = 0; p < 4; ++p) {
      int m = n0 + (tx << 2) + p;
      if (m < NM) Tb[(size_t)r * NM + m] = acc[q][p];
    }
  }
}

// ---------------- F[b] = Tmp[b] @ Up_b^T  -> Ffull[0:256][0:256] ------------
__global__ __launch_bounds__(256)
void gemm2_k(const float* __restrict__ U, const int* __restrict__ idx,
             const float* __restrict__ Tmp, float* __restrict__ Ff) {
  const int b  = blockIdx.z;
  const int m0 = blockIdx.y << 6;
  const int n0 = blockIdx.x << 6;
  const int tid = threadIdx.x;
  __shared__ float As[16][64];
  __shared__ float Bs[16][64];
  const int ar = tid >> 2, ac = (tid & 3) << 2;
  const int jr = tid >> 2, kc = (tid & 3) << 2;
  const int tx = tid & 15, ty = tid >> 4;
  const float* Arow = Tmp + ((size_t)b * NE + m0 + ar) * NM;
  const float* Brow = U + (size_t)idx[b * NE + n0 + jr] * NFM + NUN;
  float acc[4][4] = {};
  for (int l0 = 0; l0 < NM; l0 += 16) {
    float4 av = *(const float4*)(Arow + l0 + ac);
    As[ac + 0][ar] = av.x; As[ac + 1][ar] = av.y;
    As[ac + 2][ar] = av.z; As[ac + 3][ar] = av.w;
    float4 bv = *(const float4*)(Brow + l0 + kc);
    Bs[kc + 0][jr] = bv.x; Bs[kc + 1][jr] = bv.y;
    Bs[kc + 2][jr] = bv.z; Bs[kc + 3][jr] = bv.w;
    __syncthreads();
#pragma unroll
    for (int kk = 0; kk < 16; ++kk) {
      float4 a4 = *(const float4*)(&As[kk][ty << 2]);
      float4 b4 = *(const float4*)(&Bs[kk][tx << 2]);
      float a[4] = {a4.x, a4.y, a4.z, a4.w};
      float bb[4] = {b4.x, b4.y, b4.z, b4.w};
#pragma unroll
      for (int q = 0; q < 4; ++q)
#pragma unroll
        for (int p = 0; p < 4; ++p) acc[q][p] = fmaf(a[q], bb[p], acc[q][p]);
    }
    __syncthreads();
  }
  float* Fb = Ff + (size_t)b * NF * NF;
#pragma unroll
  for (int q = 0; q < 4; ++q) {
    int i = m0 + (ty << 2) + q;
#pragma unroll
    for (int p = 0; p < 4; ++p) {
      int j = n0 + (tx << 2) + p;
      Fb[(size_t)i * NF + j] = acc[q][p];
    }
  }
}

// ---------------- edges ---------------
__global__ __launch_bounds__(256)
void fill_edges_k(const float* __restrict__ U, const int* __restrict__ idx,
                  float* __restrict__ Ff) {
  const int b = blockIdx.x;
  const int tid = threadIdx.x;
  float* Fb = Ff + (size_t)b * NF * NF;
  const int gr = idx[b * NE + tid];
#pragma unroll 4
  for (int u = 0; u < NUN; ++u) {
    float v = U[(size_t)gr * NFM + u];
    Fb[(size_t)tid * NF + NE + u] = v;
    Fb[(size_t)(NE + u) * NF + tid] = -v;
  }
  if (tid < NUN) {
    for (int v = 0; v < NUN; ++v) Fb[(size_t)(NE + tid) * NF + NE + v] = 0.f;
  }
}

// ---------------- Pfaffian: blocked Parlett-Reid, single-wave factor --------
// Invariant: A_cur[i][j] = snapshot[i][j] + sum_m (tau_m[i]c_m[j]-c_m[i]tau_m[j])
// snapshot: P (panel cols) + global A (trailing cols). Wave 0 factors the
// panel wave-synchronously (no block barriers); all waves apply the rank-16
// trailing update once per panel.
__global__ __launch_bounds__(512)
void pfpanel_k(float* __restrict__ Ff, float* __restrict__ out) {
  const int b = blockIdx.x;
  float* __restrict__ A = Ff + (size_t)b * NF * NF;
  const int tid = threadIdx.x;
  __shared__ __align__(16) float P[NF * PP];
  __shared__ __align__(16) float s_tau[PAIRS][NF];
  __shared__ __align__(16) float s_c[PAIRS][NF];
  __shared__ float s_vk1;

  float sign = 1.f, logabs = 0.f;  // lane 0 of wave 0 only

  for (int k0 = 0; k0 < NF; k0 += WP) {
    const int pend = k0 + WP;

    // ---- panel load (only rows > k0 are alive) ----
    if (tid > k0 && tid < NF) {
      const float* src = A + (size_t)tid * NF + k0;
      float* dst = P + tid * PP;
      float4 v0 = *(const float4*)(src);
      float4 v1 = *(const float4*)(src + 4);
      float4 v2 = *(const float4*)(src + 8);
      float4 v3 = *(const float4*)(src + 12);
      dst[0]=v0.x;  dst[1]=v0.y;  dst[2]=v0.z;  dst[3]=v0.w;
      dst[4]=v1.x;  dst[5]=v1.y;  dst[6]=v1.z;  dst[7]=v1.w;
      dst[8]=v2.x;  dst[9]=v2.y;  dst[10]=v2.z; dst[11]=v2.w;
      dst[12]=v3.x; dst[13]=v3.y; dst[14]=v3.z; dst[15]=v3.w;
    }
    __syncthreads();

    if (tid < 64) {
      const int lane = tid;
      for (int mp = 0; mp < PAIRS; ++mp) {
        const int k = k0 + 2 * mp, lc = 2 * mp, lc1 = lc + 1;

        // ---- column k + deferred corrections ----
        float v[NW];
#pragma unroll
        for (int w = 0; w < NW; ++w) {
          int i = lane + 64 * w;
          v[w] = 0.f;
          if (i > k && i < NF) v[w] = P[i * PP + lc];
        }
        for (int m = 0; m < mp; ++m) {
          float cm = s_c[m][k], tm = s_tau[m][k];
#pragma unroll
          for (int w = 0; w < NW; ++w) {
            int i = lane + 64 * w;
            if (i > k && i < NF)
              v[w] = fmaf(s_tau[m][i], cm, fmaf(-s_c[m][i], tm, v[w]));
          }
        }
        // ---- argmax butterfly carrying (key, value) ----
        ull pk = 0; float pv = 0.f;
#pragma unroll
        for (int w = 0; w < NW; ++w) {
          int i = lane + 64 * w;
          if (i > k && i < NF) {
            if (i == k + 1) s_vk1 = v[w];
            ull cand = ((ull)__float_as_uint(fabsf(v[w])) << 32) | (ull)(NF - i);
            if (cand > pk) { pk = cand; pv = v[w]; }
          }
        }
#pragma unroll
        for (int m = 32; m > 0; m >>= 1) {
          ull opk = __shfl_xor(pk, m, 64);
          float opv = __shfl_xor(pv, m, 64);
          if (opk > pk) { pk = opk; pv = opv; }
        }
        const int kp = NF - (int)(pk & 0xffffffffULL);
        const float pivot = -pv;
        const float invp = 1.f / pivot;
        if (lane == 0) {
          if (kp != k + 1) sign = -sign;
          sign *= (pivot > 0.f ? 1.f : (pivot < 0.f ? -1.f : 0.f));
          logabs += logf(fabsf(pivot));
        }

        float cc[NW], tt[NW];
#pragma unroll
        for (int w = 0; w < NW; ++w) { cc[w] = 0.f; tt[w] = 0.f; }

        if (kp == k + 1) {
          // ================= case A: no swap =================
#pragma unroll
          for (int w = 0; w < NW; ++w) {
            int i = lane + 64 * w;
            if (i > k + 1 && i < NF) { tt[w] = -v[w] * invp; cc[w] = P[i * PP + lc1]; }
          }
          for (int m = 0; m < mp; ++m) {
            float cm1 = s_c[m][k + 1], tm1 = s_tau[m][k + 1];
#pragma unroll
            for (int w = 0; w < NW; ++w) {
              int i = lane + 64 * w;
              if (i > k + 1 && i < NF)
                cc[w] = fmaf(s_tau[m][i], cm1, fmaf(-s_c[m][i], tm1, cc[w]));
            }
          }
        } else if (kp < pend) {
          // ================= case B: in-panel swap =================
          LGKM0();
          float vk1 = s_vk1;
          const int lckp = kp - k0;
          if (lane < WP) {
            float a = P[(k + 1) * PP + lane], b2 = P[kp * PP + lane];
            P[(k + 1) * PP + lane] = b2; P[kp * PP + lane] = a;
          } else if (lane < WP + 2 * mp) {
            int j = lane - WP, m = j >> 1;
            float* arr = (j & 1) ? &s_c[m][0] : &s_tau[m][0];
            float a = arr[k + 1], b2 = arr[kp];
            arr[k + 1] = b2; arr[kp] = a;
          }
          LGKM0();
          // global trailing row: logical row kp inherits old row k+1 cells
          if (pend < NF) {
#pragma unroll
            for (int w = 0; w < NW; ++w) {
              int j = pend + lane + 64 * w;
              if (j < NF) A[(size_t)kp * NF + j] = A[(size_t)(k + 1) * NF + j];
            }
          }
          // P column swap lc1 <-> lckp over live rows
#pragma unroll
          for (int w = 0; w < NW; ++w) {
            int i = lane + 64 * w;
            if (i > k + 1 && i < NF) {
              float a = P[i * PP + lc1], b2 = P[i * PP + lckp];
              P[i * PP + lc1] = b2; P[i * PP + lckp] = a;
            }
          }
          LGKM0();
          // staging (post-swap, uniform)
#pragma unroll
          for (int w = 0; w < NW; ++w) {
            int i = lane + 64 * w;
            if (i > k + 1 && i < NF) {
              float vi = (i == kp) ? vk1 : v[w];
              tt[w] = -vi * invp;
              cc[w] = P[i * PP + lc1];
            }
          }
          for (int m = 0; m < mp; ++m) {
            float cm1 = s_c[m][k + 1], tm1 = s_tau[m][k + 1];
#pragma unroll
            for (int w = 0; w < NW; ++w) {
              int i = lane + 64 * w;
              if (i > k + 1 && i < NF)
                cc[w] = fmaf(s_tau[m][i], cm1, fmaf(-s_c[m][i], tm1, cc[w]));
            }
          }
          VM0();
        } else {
          // ================= case C: trailing swap =================
          LGKM0();
          float vk1 = s_vk1;
          float gv[NW], pvv[NW];
#pragma unroll
          for (int w = 0; w < NW; ++w) {    // issue global column loads early
            int i = lane + 64 * w;
            gv[w] = 0.f;
            if (i > k + 1 && i < NF && i != kp) gv[w] = A[(size_t)i * NF + kp];
          }
#pragma unroll
          for (int w = 0; w < NW; ++w) {    // old panel col lc1 (for writeback & c_kp)
            int i = lane + 64 * w;
            pvv[w] = 0.f;
            if (i > k + 1 && i < NF) pvv[w] = P[i * PP + lc1];
          }
#pragma unroll
          for (int w = 0; w < NW; ++w) {
            int i = lane + 64 * w;
            if (i > k + 1 && i < NF && i != kp) cc[w] = gv[w];
          }
          float ckp_acc = 0.f;
          for (int m = 0; m < mp; ++m) {
            float ckpm = s_c[m][kp], tkpm = s_tau[m][kp];     // pre-swap entries
            float cm1 = s_c[m][k + 1], tm1 = s_tau[m][k + 1];
            ckp_acc = fmaf(tkpm, cm1, fmaf(-ckpm, tm1, ckp_acc));
#pragma unroll
            for (int w = 0; w < NW; ++w) {
              int i = lane + 64 * w;
              if (i > k + 1 && i < NF && i != kp)
                cc[w] = fmaf(s_tau[m][i], ckpm, fmaf(-s_c[m][i], tkpm, cc[w]));
            }
          }
#pragma unroll
          for (int w = 0; w < NW; ++w) {
            int i = lane + 64 * w;
            if (i > k + 1 && i < NF) {
              if (i == kp) { tt[w] = -vk1 * invp; cc[w] = -(pvv[w] + ckp_acc); }
              else         { tt[w] = -v[w] * invp; }
            }
          }
          // global writebacks (corrections cancel: raw snapshot values)
#pragma unroll
          for (int w = 0; w < NW; ++w) {
            int i = lane + 64 * w;
            if (i > k + 1 && i < NF) {
              if (i == kp) {
                A[(size_t)kp * NF + kp] = 0.f;
              } else {
                A[(size_t)i * NF + kp] = pvv[w];
                if (i >= pend) A[(size_t)kp * NF + i] = -pvv[w];
              }
            }
          }
          LGKM0();   // pvv reads (incl P[kp][lc1]) done before row overwrite
          // P row kp <- old P row k+1 (panel cols)
          if (lane < WP) P[kp * PP + lane] = P[(k + 1) * PP + lane];
          // tau/c entries: position kp gets old k+1 entries (k+1 side dead)
          if (lane < mp) {
            int m = lane;
            float cm1 = s_c[m][k + 1], tm1 = s_tau[m][k + 1];
            s_c[m][kp] = cm1; s_tau[m][kp] = tm1;
          }
          VM0();
        }

        // ---- store pair mp ----
#pragma unroll
        for (int w = 0; w < NW; ++w) {
          int i = lane + 64 * w;
          if (i < NF) { s_tau[mp][i] = tt[w]; s_c[mp][i] = cc[w]; }
        }
        LGKM0();
      }
    }
    __syncthreads();

    // ---- panel-end: streaming rank-16 update of trailing block ----
    if (pend < NF) {
      const int ty = tid >> 6, tx = tid & 63;
      const int nch = (NF - pend) >> 2;
      for (int i = pend + ty; i < NF; i += 8) {
        float ti[PAIRS], ci[PAIRS];
#pragma unroll
        for (int m = 0; m < PAIRS; ++m) { ti[m] = s_tau[m][i]; ci[m] = s_c[m][i]; }
        for (int j4 = tx; j4 < nch; j4 += 64) {
          const int j = pend + (j4 << 2);
          float* ap = A + (size_t)i * NF + j;
          float4 a = *(float4*)ap;
#pragma unroll
          for (int m = 0; m < PAIRS; ++m) {
            const float4 cj = *(const float4*)(&s_c[m][j]);
            const float4 tj = *(const float4*)(&s_tau[m][j]);
            a.x = fmaf(ti[m], cj.x, fmaf(-ci[m], tj.x, a.x));
            a.y = fmaf(ti[m], cj.y, fmaf(-ci[m], tj.y, a.y));
            a.z = fmaf(ti[m], cj.z, fmaf(-ci[m], tj.z, a.z));
            a.w = fmaf(ti[m], cj.w, fmaf(-ci[m], tj.w, a.w));
          }
          *(float4*)ap = a;
        }
      }
    }
    __syncthreads();
  }

  if (tid == 0) { out[b] = sign; out[NB + b] = logabs; }
}

extern "C" void kernel_launch(void* const* d_in, const int* in_sizes, int n_in,
                              void* d_out, int out_size, void* d_ws, size_t ws_size,
                              hipStream_t stream) {
  const float* U  = (const float*)d_in[0];
  const float* J  = (const float*)d_in[1];
  const int* idx  = (const int*)d_in[2];
  float* out = (float*)d_out;
  float* ws = (float*)d_ws;

  float* Ja  = ws;                          // 480*480
  float* Tmp = Ja + (size_t)NM * NM;        // 32*256*480
  float* Ff  = Tmp + (size_t)NB * NE * NM;  // 32*288*288

  build_ja_k<<<dim3(256), dim3(256), 0, stream>>>(J, Ja);
  gemm1_k<<<dim3(8, 4, NB), dim3(256), 0, stream>>>(U, idx, Ja, Tmp);
  gemm2_k<<<dim3(4, 4, NB), dim3(256), 0, stream>>>(U, idx, Tmp, Ff);
  fill_edges_k<<<dim3(NB), dim3(256), 0, stream>>>(U, idx, Ff);
  pfpanel_k<<<dim3(NB), dim3(512), 0, stream>>>(Ff, out);
}

// Round 5
// 624.434 us; speedup vs baseline: 1.0988x; 1.0988x over previous
//
#include <hip/hip_runtime.h>
#include <hip/hip_bf16.h>
#include <math.h>

#define NFM 512   // NFMODES
#define NE  256
#define NUN 32    // NUNPAIRED
#define NM  480   // NMODES
#define NB  32    // BATCH
#define NF  288   // NE + NUN  (Ffull dim)
#define WP  16    // panel width
#define PAIRS 8   // WP/2
#define PP  17    // panel LDS pitch (odd -> conflict-free)

typedef unsigned long long ull;

// ---------------- Ja = (J - J^T)/2 ----------------
__global__ __launch_bounds__(256)
void build_ja_k(const float* __restrict__ J, float* __restrict__ Ja) {
  int t = blockIdx.x * blockDim.x + threadIdx.x;
  int stride = gridDim.x * blockDim.x;
  for (int e = t; e < NM * NM; e += stride) {
    int i = e / NM, j = e - i * NM;
    Ja[e] = 0.5f * (J[i * NM + j] - J[j * NM + i]);
  }
}

// ---------------- Tmp[b] (256x480) = Up_b @ Ja ----------
__global__ __launch_bounds__(256)
void gemm1_k(const float* __restrict__ U, const int* __restrict__ idx,
             const float* __restrict__ Ja, float* __restrict__ Tmp) {
  const int b  = blockIdx.z;
  const int m0 = blockIdx.y << 6;
  const int n0 = blockIdx.x << 6;
  const int tid = threadIdx.x;
  __shared__ float As[16][64];
  __shared__ float Bs[16][64];
  const int ar = tid >> 2, ac = (tid & 3) << 2;
  const int br = tid >> 4, bc = (tid & 15) << 2;
  const int tx = tid & 15, ty = tid >> 4;
  const float* Arow = U + (size_t)idx[b * NE + m0 + ar] * NFM + NUN;
  float acc[4][4] = {};
  for (int l0 = 0; l0 < NM; l0 += 16) {
    float4 av = *(const float4*)(Arow + l0 + ac);
    As[ac + 0][ar] = av.x; As[ac + 1][ar] = av.y;
    As[ac + 2][ar] = av.z; As[ac + 3][ar] = av.w;
    float4 bv = make_float4(0.f, 0.f, 0.f, 0.f);
    if (n0 + bc < NM) bv = *(const float4*)(Ja + (size_t)(l0 + br) * NM + n0 + bc);
    *(float4*)(&Bs[br][bc]) = bv;
    __syncthreads();
#pragma unroll
    for (int kk = 0; kk < 16; ++kk) {
      float4 a4 = *(const float4*)(&As[kk][ty << 2]);
      float4 b4 = *(const float4*)(&Bs[kk][tx << 2]);
      float a[4] = {a4.x, a4.y, a4.z, a4.w};
      float bb[4] = {b4.x, b4.y, b4.z, b4.w};
#pragma unroll
      for (int q = 0; q < 4; ++q)
#pragma unroll
        for (int p = 0; p < 4; ++p) acc[q][p] = fmaf(a[q], bb[p], acc[q][p]);
    }
    __syncthreads();
  }
  float* Tb = Tmp + (size_t)b * NE * NM;
#pragma unroll
  for (int q = 0; q < 4; ++q) {
    int r = m0 + (ty << 2) + q;
#pragma unroll
    for (int p = 0; p < 4; ++p) {
      int m = n0 + (tx << 2) + p;
      if (m < NM) Tb[(size_t)r * NM + m] = acc[q][p];
    }
  }
}

// ---------------- F[b] = Tmp[b] @ Up_b^T  -> Ffull[0:256][0:256] ------------
__global__ __launch_bounds__(256)
void gemm2_k(const float* __restrict__ U, const int* __restrict__ idx,
             const float* __restrict__ Tmp, float* __restrict__ Ff) {
  const int b  = blockIdx.z;
  const int m0 = blockIdx.y << 6;
  const int n0 = blockIdx.x << 6;
  const int tid = threadIdx.x;
  __shared__ float As[16][64];
  __shared__ float Bs[16][64];
  const int ar = tid >> 2, ac = (tid & 3) << 2;
  const int jr = tid >> 2, kc = (tid & 3) << 2;
  const int tx = tid & 15, ty = tid >> 4;
  const float* Arow = Tmp + ((size_t)b * NE + m0 + ar) * NM;
  const float* Brow = U + (size_t)idx[b * NE + n0 + jr] * NFM + NUN;
  float acc[4][4] = {};
  for (int l0 = 0; l0 < NM; l0 += 16) {
    float4 av = *(const float4*)(Arow + l0 + ac);
    As[ac + 0][ar] = av.x; As[ac + 1][ar] = av.y;
    As[ac + 2][ar] = av.z; As[ac + 3][ar] = av.w;
    float4 bv = *(const float4*)(Brow + l0 + kc);
    Bs[kc + 0][jr] = bv.x; Bs[kc + 1][jr] = bv.y;
    Bs[kc + 2][jr] = bv.z; Bs[kc + 3][jr] = bv.w;
    __syncthreads();
#pragma unroll
    for (int kk = 0; kk < 16; ++kk) {
      float4 a4 = *(const float4*)(&As[kk][ty << 2]);
      float4 b4 = *(const float4*)(&Bs[kk][tx << 2]);
      float a[4] = {a4.x, a4.y, a4.z, a4.w};
      float bb[4] = {b4.x, b4.y, b4.z, b4.w};
#pragma unroll
      for (int q = 0; q < 4; ++q)
#pragma unroll
        for (int p = 0; p < 4; ++p) acc[q][p] = fmaf(a[q], bb[p], acc[q][p]);
    }
    __syncthreads();
  }
  float* Fb = Ff + (size_t)b * NF * NF;
#pragma unroll
  for (int q = 0; q < 4; ++q) {
    int i = m0 + (ty << 2) + q;
#pragma unroll
    for (int p = 0; p < 4; ++p) {
      int j = n0 + (tx << 2) + p;
      Fb[(size_t)i * NF + j] = acc[q][p];
    }
  }
}

// ---------------- edges ---------------
__global__ __launch_bounds__(256)
void fill_edges_k(const float* __restrict__ U, const int* __restrict__ idx,
                  float* __restrict__ Ff) {
  const int b = blockIdx.x;
  const int tid = threadIdx.x;
  float* Fb = Ff + (size_t)b * NF * NF;
  const int gr = idx[b * NE + tid];
#pragma unroll 4
  for (int u = 0; u < NUN; ++u) {
    float v = U[(size_t)gr * NFM + u];
    Fb[(size_t)tid * NF + NE + u] = v;
    Fb[(size_t)(NE + u) * NF + tid] = -v;
  }
  if (tid < NUN) {
    for (int v = 0; v < NUN; ++v) Fb[(size_t)(NE + tid) * NF + NE + v] = 0.f;
  }
}

// ---------------- Pfaffian: blocked Parlett-Reid with LDS patch columns -----
// Invariant: A_cur[i][j] = snapshot[i][j] + sum_m (tau_m[i]c_m[j]-c_m[i]tau_m[j])
// snapshot = P (panel cols, LDS) + patches (displaced cols, LDS) + global A.
// No global writes during the panel; trailing rank-16 streaming pass per panel
// materializes everything (patch-aware base selection).
__global__ __launch_bounds__(512)
void pfpanel_k(float* __restrict__ Ff, float* __restrict__ out) {
  const int b = blockIdx.x;
  float* __restrict__ A = Ff + (size_t)b * NF * NF;
  const int tid = threadIdx.x;
  __shared__ __align__(16) float P[NF * PP];
  __shared__ __align__(16) float s_tau[PAIRS][NF];
  __shared__ __align__(16) float s_c[PAIRS][NF];
  __shared__ __align__(16) float s_patch[PAIRS][NF];
  __shared__ __align__(16) float s_colbuf[NF];
  __shared__ __align__(16) float s_oldrow[WP];
  __shared__ ull s_red[8];
  __shared__ int s_patch_col[PAIRS];
  __shared__ __align__(4) unsigned char s_pmask[NF + 4];

  float sign = 1.f, logabs = 0.f;   // thread 0 only

  for (int k0 = 0; k0 < NF; k0 += WP) {
    const int pend = k0 + WP;
    int npl = 0;   // patch count (tracked identically by every thread)

    // ---- panel load: P[r][0..15] = A[r][k0..k0+15] ----
    for (int e = tid; e < NF * 4; e += 512) {
      int r = e >> 2, c4 = (e & 3) << 2;
      float4 v = *(const float4*)(A + (size_t)r * NF + k0 + c4);
      float* d = P + r * PP + c4;
      d[0] = v.x; d[1] = v.y; d[2] = v.z; d[3] = v.w;
    }
    __syncthreads();

#pragma unroll 1
    for (int mp = 0; mp < PAIRS; ++mp) {
      const int k = k0 + 2 * mp, lc = 2 * mp, lc1 = lc + 1;

      // ---------- phase 1: column k (+ deferred corrections) & argmax -------
      ull pk = 0;
      if (tid > k && tid < NF) {
        float v = P[tid * PP + lc];
        for (int m = 0; m < mp; ++m)
          v = fmaf(s_tau[m][tid], s_c[m][k], fmaf(-s_c[m][tid], s_tau[m][k], v));
        s_colbuf[tid] = v;
        pk = ((ull)__float_as_uint(fabsf(v)) << 32) | (ull)(NF - tid);
      }
#pragma unroll
      for (int m = 32; m > 0; m >>= 1) {
        ull o = __shfl_xor(pk, m, 64);
        if (o > pk) pk = o;
      }
      if ((tid & 63) == 0) s_red[tid >> 6] = pk;
      __syncthreads();                                   // B1
      ull best = s_red[0];
#pragma unroll
      for (int w = 1; w < 8; ++w) if (s_red[w] > best) best = s_red[w];
      const int kp = NF - (int)(best & 0xffffffffULL);
      const float pivot = -s_colbuf[kp];
      const float invp = 1.f / pivot;
      if (tid == 0) {
        if (kp != k + 1) sign = -sign;
        sign *= (pivot > 0.f ? 1.f : (pivot < 0.f ? -1.f : 0.f));
        logabs += logf(fabsf(pivot));
      }
      const bool inpanel = (kp < pend);
      float gvr = 0.f;

      // ---------- phase 2: swap (B: in-panel, C: trailing via patch) --------
      if (kp != k + 1) {
        if (inpanel) {
          const int lckp = kp - k0;
          if (tid > k + 1 && tid < NF && tid != kp) {
            // column swap lc1 <-> lckp (rows not involved in the row swap)
            float a = P[tid * PP + lc1], b2 = P[tid * PP + lckp];
            P[tid * PP + lc1] = b2; P[tid * PP + lckp] = a;
          } else if (tid >= NF && tid < NF + WP) {
            // row swap k+1 <-> kp (panel cols, minus the 2x2 intersection)
            int c = tid - NF;
            if (c != lc1 && c != lckp) {
              float a = P[(k + 1) * PP + c], b2 = P[kp * PP + c];
              P[(k + 1) * PP + c] = b2; P[kp * PP + c] = a;
            }
          } else if (tid == NF + WP) {
            // 2x2 intersection, single thread (reads old values first)
            float a = P[kp * PP + lc1];        // old A[kp][k+1]
            float b2 = P[(k + 1) * PP + lckp]; // old A[k+1][kp]
            P[(k + 1) * PP + lc1] = 0.f;   P[(k + 1) * PP + lckp] = a;
            P[kp * PP + lc1] = b2;         P[kp * PP + lckp] = 0.f;
          } else if (tid >= NF + 24 && tid < NF + 24 + mp) {
            int m = tid - (NF + 24);
            float a = s_tau[m][k + 1]; s_tau[m][k + 1] = s_tau[m][kp]; s_tau[m][kp] = a;
            float c2 = s_c[m][k + 1];  s_c[m][k + 1] = s_c[m][kp];    s_c[m][kp] = c2;
          }
        } else {
          // ---- case C: record patch, gather snapshot column kp (pre-swap) --
          const int q = npl;
          if (tid < NF) {
            s_patch[q][tid] = (tid == kp) ? 0.f : P[tid * PP + lc1];
            if (tid >= pend && tid != kp) {
              int colq = -1, rowq = -1;
              for (int qq = 0; qq < npl; ++qq) {
                if (s_patch_col[qq] == kp)  colq = qq;
                if (s_patch_col[qq] == tid) rowq = qq;
              }
              if (colq >= 0)      gvr = s_patch[colq][tid];
              else if (rowq >= 0) gvr = -s_patch[rowq][kp];
              else                gvr = A[(size_t)tid * NF + kp];
            }
          } else if (tid >= NF && tid < NF + WP) {
            int c = tid - NF;
            float old = P[kp * PP + c];
            s_oldrow[c] = old;
            P[kp * PP + c] = P[(k + 1) * PP + c];
          } else if (tid == NF + WP) {
            s_patch_col[q] = kp;
          } else if (tid >= NF + 24 && tid < NF + 24 + mp) {
            int m = tid - (NF + 24);
            float a = s_tau[m][k + 1]; s_tau[m][k + 1] = s_tau[m][kp]; s_tau[m][kp] = a;
            float c2 = s_c[m][k + 1];  s_c[m][k + 1] = s_c[m][kp];    s_c[m][kp] = c2;
          }
          npl++;   // uniform
        }
        __syncthreads();                                 // B2
      }

      // ---------- phase 3: stage pair (tau, c); patch-entry swaps -----------
      if (tid > k + 1 && tid < NF) {
        float vpost = (tid == kp) ? s_colbuf[k + 1] : s_colbuf[tid];
        float tt = -vpost * invp;
        float cc;
        if (inpanel)            cc = P[tid * PP + lc1];
        else if (tid < pend)    cc = -s_oldrow[tid - k0];
        else if (tid == kp)     cc = -s_oldrow[lc1];
        else                    cc = gvr;
        for (int m = 0; m < mp; ++m)
          cc = fmaf(s_tau[m][tid], s_c[m][k + 1],
                    fmaf(-s_c[m][tid], s_tau[m][k + 1], cc));
        s_tau[mp][tid] = tt; s_c[mp][tid] = cc;
      } else if (tid >= NF + 40 && kp != k + 1) {
        int nq = npl - (inpanel ? 0 : 1);   // exclude the patch created this step
        int qq = tid - (NF + 40);
        if (qq < nq) {
          float a = s_patch[qq][k + 1];
          s_patch[qq][k + 1] = s_patch[qq][kp];
          s_patch[qq][kp] = a;
        }
      }
      __syncthreads();                                   // B3
    }

    // ---- pmask: latest patch id per trailing column ----
    if (tid < NF) {
      unsigned char m = 0;
      for (int q = 0; q < npl; ++q)
        if (s_patch_col[q] == tid) m = (unsigned char)(q + 1);
      s_pmask[tid] = m;
    } else if (tid < NF + 4) {
      s_pmask[NF + (tid - NF)] = 0;
    }
    __syncthreads();

    // ---- panel-end: patch-aware streaming rank-16 update of trailing block -
    if (pend < NF) {
      const int ty = tid >> 6, tx = tid & 63;
      const int nch = (NF - pend) >> 2;
      for (int i = pend + ty; i < NF; i += 8) {
        const int rq = s_pmask[i];
        float ti[PAIRS], ci[PAIRS];
#pragma unroll
        for (int m = 0; m < PAIRS; ++m) { ti[m] = s_tau[m][i]; ci[m] = s_c[m][i]; }
        for (int j4 = tx; j4 < nch; j4 += 64) {
          const int j = pend + (j4 << 2);
          float* ap = A + (size_t)i * NF + j;
          float4 a;
          unsigned pm4 = *(const unsigned*)(&s_pmask[j]);
          if (rq) {
            const float* pp = &s_patch[rq - 1][j];
            a = make_float4(-pp[0], -pp[1], -pp[2], -pp[3]);
          } else if (pm4 == 0) {
            a = *(const float4*)ap;
          } else {
            int q0 = s_pmask[j], q1 = s_pmask[j + 1], q2 = s_pmask[j + 2], q3 = s_pmask[j + 3];
            a.x = q0 ? s_patch[q0 - 1][i] : ap[0];
            a.y = q1 ? s_patch[q1 - 1][i] : ap[1];
            a.z = q2 ? s_patch[q2 - 1][i] : ap[2];
            a.w = q3 ? s_patch[q3 - 1][i] : ap[3];
          }
#pragma unroll
          for (int m = 0; m < PAIRS; ++m) {
            const float4 cj = *(const float4*)(&s_c[m][j]);
            const float4 tj = *(const float4*)(&s_tau[m][j]);
            a.x = fmaf(ti[m], cj.x, fmaf(-ci[m], tj.x, a.x));
            a.y = fmaf(ti[m], cj.y, fmaf(-ci[m], tj.y, a.y));
            a.z = fmaf(ti[m], cj.z, fmaf(-ci[m], tj.z, a.z));
            a.w = fmaf(ti[m], cj.w, fmaf(-ci[m], tj.w, a.w));
          }
          *(float4*)ap = a;
        }
      }
    }
    __syncthreads();
  }

  if (tid == 0) { out[b] = sign; out[NB + b] = logabs; }
}

extern "C" void kernel_launch(void* const* d_in, const int* in_sizes, int n_in,
                              void* d_out, int out_size, void* d_ws, size_t ws_size,
                              hipStream_t stream) {
  const float* U  = (const float*)d_in[0];
  const float* J  = (const float*)d_in[1];
  const int* idx  = (const int*)d_in[2];
  float* out = (float*)d_out;
  float* ws = (float*)d_ws;

  float* Ja  = ws;                          // 480*480
  float* Tmp = Ja + (size_t)NM * NM;        // 32*256*480
  float* Ff  = Tmp + (size_t)NB * NE * NM;  // 32*288*288

  build_ja_k<<<dim3(256), dim3(256), 0, stream>>>(J, Ja);
  gemm1_k<<<dim3(8, 4, NB), dim3(256), 0, stream>>>(U, idx, Ja, Tmp);
  gemm2_k<<<dim3(4, 4, NB), dim3(256), 0, stream>>>(U, idx, Tmp, Ff);
  fill_edges_k<<<dim3(NB), dim3(256), 0, stream>>>(U, idx, Ff);
  pfpanel_k<<<dim3(NB), dim3(512), 0, stream>>>(Ff, out);
}

// Round 6
// 470.212 us; speedup vs baseline: 1.4591x; 1.3280x over previous
//
#include <hip/hip_runtime.h>
#include <hip/hip_bf16.h>
#include <math.h>

#define NFM 512   // NFMODES
#define NE  256
#define NUN 32    // NUNPAIRED
#define NM  480   // NMODES
#define NB  32    // BATCH
#define NF  288   // NE + NUN  (Ffull dim)
#define WP  16    // panel width
#define PAIRS 8   // WP/2
#define PP  18    // panel LDS pitch (even -> float2-aligned)
#define THETA 0.03125f

typedef unsigned long long ull;

// ---------------- Ja = (J - J^T)/2 ----------------
__global__ __launch_bounds__(256)
void build_ja_k(const float* __restrict__ J, float* __restrict__ Ja) {
  int t = blockIdx.x * blockDim.x + threadIdx.x;
  int stride = gridDim.x * blockDim.x;
  for (int e = t; e < NM * NM; e += stride) {
    int i = e / NM, j = e - i * NM;
    Ja[e] = 0.5f * (J[i * NM + j] - J[j * NM + i]);
  }
}

// ---------------- Tmp[b] (256x480) = Up_b @ Ja ----------
__global__ __launch_bounds__(256)
void gemm1_k(const float* __restrict__ U, const int* __restrict__ idx,
             const float* __restrict__ Ja, float* __restrict__ Tmp) {
  const int b  = blockIdx.z;
  const int m0 = blockIdx.y << 6;
  const int n0 = blockIdx.x << 6;
  const int tid = threadIdx.x;
  __shared__ float As[16][64];
  __shared__ float Bs[16][64];
  const int ar = tid >> 2, ac = (tid & 3) << 2;
  const int br = tid >> 4, bc = (tid & 15) << 2;
  const int tx = tid & 15, ty = tid >> 4;
  const float* Arow = U + (size_t)idx[b * NE + m0 + ar] * NFM + NUN;
  float acc[4][4] = {};
  for (int l0 = 0; l0 < NM; l0 += 16) {
    float4 av = *(const float4*)(Arow + l0 + ac);
    As[ac + 0][ar] = av.x; As[ac + 1][ar] = av.y;
    As[ac + 2][ar] = av.z; As[ac + 3][ar] = av.w;
    float4 bv = make_float4(0.f, 0.f, 0.f, 0.f);
    if (n0 + bc < NM) bv = *(const float4*)(Ja + (size_t)(l0 + br) * NM + n0 + bc);
    *(float4*)(&Bs[br][bc]) = bv;
    __syncthreads();
#pragma unroll
    for (int kk = 0; kk < 16; ++kk) {
      float4 a4 = *(const float4*)(&As[kk][ty << 2]);
      float4 b4 = *(const float4*)(&Bs[kk][tx << 2]);
      float a[4] = {a4.x, a4.y, a4.z, a4.w};
      float bb[4] = {b4.x, b4.y, b4.z, b4.w};
#pragma unroll
      for (int q = 0; q < 4; ++q)
#pragma unroll
        for (int p = 0; p < 4; ++p) acc[q][p] = fmaf(a[q], bb[p], acc[q][p]);
    }
    __syncthreads();
  }
  float* Tb = Tmp + (size_t)b * NE * NM;
#pragma unroll
  for (int q = 0; q < 4; ++q) {
    int r = m0 + (ty << 2) + q;
#pragma unroll
    for (int p = 0; p < 4; ++p) {
      int m = n0 + (tx << 2) + p;
      if (m < NM) Tb[(size_t)r * NM + m] = acc[q][p];
    }
  }
}

// ---------------- F[b] = Tmp[b] @ Up_b^T  -> Ffull[0:256][0:256] ------------
__global__ __launch_bounds__(256)
void gemm2_k(const float* __restrict__ U, const int* __restrict__ idx,
             const float* __restrict__ Tmp, float* __restrict__ Ff) {
  const int b  = blockIdx.z;
  const int m0 = blockIdx.y << 6;
  const int n0 = blockIdx.x << 6;
  const int tid = threadIdx.x;
  __shared__ float As[16][64];
  __shared__ float Bs[16][64];
  const int ar = tid >> 2, ac = (tid & 3) << 2;
  const int jr = tid >> 2, kc = (tid & 3) << 2;
  const int tx = tid & 15, ty = tid >> 4;
  const float* Arow = Tmp + ((size_t)b * NE + m0 + ar) * NM;
  const float* Brow = U + (size_t)idx[b * NE + n0 + jr] * NFM + NUN;
  float acc[4][4] = {};
  for (int l0 = 0; l0 < NM; l0 += 16) {
    float4 av = *(const float4*)(Arow + l0 + ac);
    As[ac + 0][ar] = av.x; As[ac + 1][ar] = av.y;
    As[ac + 2][ar] = av.z; As[ac + 3][ar] = av.w;
    float4 bv = *(const float4*)(Brow + l0 + kc);
    Bs[kc + 0][jr] = bv.x; Bs[kc + 1][jr] = bv.y;
    Bs[kc + 2][jr] = bv.z; Bs[kc + 3][jr] = bv.w;
    __syncthreads();
#pragma unroll
    for (int kk = 0; kk < 16; ++kk) {
      float4 a4 = *(const float4*)(&As[kk][ty << 2]);
      float4 b4 = *(const float4*)(&Bs[kk][tx << 2]);
      float a[4] = {a4.x, a4.y, a4.z, a4.w};
      float bb[4] = {b4.x, b4.y, b4.z, b4.w};
#pragma unroll
      for (int q = 0; q < 4; ++q)
#pragma unroll
        for (int p = 0; p < 4; ++p) acc[q][p] = fmaf(a[q], bb[p], acc[q][p]);
    }
    __syncthreads();
  }
  float* Fb = Ff + (size_t)b * NF * NF;
#pragma unroll
  for (int q = 0; q < 4; ++q) {
    int i = m0 + (ty << 2) + q;
#pragma unroll
    for (int p = 0; p < 4; ++p) {
      int j = n0 + (tx << 2) + p;
      Fb[(size_t)i * NF + j] = acc[q][p];
    }
  }
}

// ---------------- edges ---------------
__global__ __launch_bounds__(256)
void fill_edges_k(const float* __restrict__ U, const int* __restrict__ idx,
                  float* __restrict__ Ff) {
  const int b = blockIdx.x;
  const int tid = threadIdx.x;
  float* Fb = Ff + (size_t)b * NF * NF;
  const int gr = idx[b * NE + tid];
#pragma unroll 4
  for (int u = 0; u < NUN; ++u) {
    float v = U[(size_t)gr * NFM + u];
    Fb[(size_t)tid * NF + NE + u] = v;
    Fb[(size_t)(NE + u) * NF + tid] = -v;
  }
  if (tid < NUN) {
    for (int v = 0; v < NUN; ++v) Fb[(size_t)(NE + tid) * NF + NE + v] = 0.f;
  }
}

// ---------------- Pfaffian: blocked Parlett-Reid, threshold pivoting --------
// Invariant: A_cur[i][j] = snapshot[i][j] + sum_m (tau_m[i]c_m[j]-c_m[i]tau_m[j])
// snapshot = P (panel cols, LDS) + global A (trailing cols).
// Common case (no swap): 2 barriers/step, tau/c staged from registers.
// Swap cases (B in-panel / C trailing): round-3/5 verified algebra, 3 barriers.
__global__ __launch_bounds__(512)
void pfpanel_k(float* __restrict__ Ff, float* __restrict__ out) {
  const int b = blockIdx.x;
  float* __restrict__ A = Ff + (size_t)b * NF * NF;
  const int tid = threadIdx.x;
  __shared__ __align__(16) float P[NF * PP];
  __shared__ __align__(16) float2 s_tc[PAIRS][NF];   // (tau, c) interleaved
  __shared__ __align__(16) float s_colbuf[NF];
  __shared__ float s_oldrow[WP];
  __shared__ ull s_red[8];

  float sign = 1.f, logabs = 0.f;   // thread 0 only

  for (int k0 = 0; k0 < NF; k0 += WP) {
    const int pend = k0 + WP;

    // ---- panel load: P[r][0..15] = A[r][k0..k0+15] ----
    for (int e = tid; e < NF * 4; e += 512) {
      int r = e >> 2, c4 = (e & 3) << 2;
      float4 v = *(const float4*)(A + (size_t)r * NF + k0 + c4);
      float2* d = (float2*)&P[r * PP + c4];
      d[0] = make_float2(v.x, v.y);
      d[1] = make_float2(v.z, v.w);
    }
    __syncthreads();

#pragma unroll 1
    for (int mp = 0; mp < PAIRS; ++mp) {
      const int k = k0 + 2 * mp, lc = 2 * mp, lc1 = lc + 1;

      // ---- phase 1: both pair columns + corrections (registers) + max -----
      float vk = 0.f, vk1 = 0.f;
      ull pk = 0;
      if (tid > k && tid < NF) {
        float2 pv = *(const float2*)&P[tid * PP + lc];
        vk = pv.x; vk1 = pv.y;
        for (int m = 0; m < mp; ++m) {
          float2 ti  = s_tc[m][tid];
          float2 tk  = s_tc[m][k];
          float2 tk1 = s_tc[m][k + 1];
          vk  = fmaf(ti.x, tk.y,  fmaf(-ti.y, tk.x,  vk));
          vk1 = fmaf(ti.x, tk1.y, fmaf(-ti.y, tk1.x, vk1));
        }
        s_colbuf[tid] = vk;
        pk = ((ull)__float_as_uint(fabsf(vk)) << 32) | (ull)(NF - tid);
      }
#pragma unroll
      for (int m = 32; m > 0; m >>= 1) {
        ull o = __shfl_xor(pk, m, 64);
        if (o > pk) pk = o;
      }
      if ((tid & 63) == 0) s_red[tid >> 6] = pk;
      __syncthreads();                                    // B1
      ull best = s_red[0];
#pragma unroll
      for (int w = 1; w < 8; ++w) if (s_red[w] > best) best = s_red[w];
      const float vmax = __uint_as_float((unsigned)(best >> 32));
      const float pivdef = -s_colbuf[k + 1];
      const bool doswap = fabsf(pivdef) < THETA * vmax;
      const int kp = doswap ? (NF - (int)(best & 0xffffffffULL)) : (k + 1);
      const float pivot = doswap ? -s_colbuf[kp] : pivdef;
      const float invp = 1.f / pivot;
      if (tid == 0) {
        if (kp != k + 1) sign = -sign;
        sign *= (pivot > 0.f ? 1.f : (pivot < 0.f ? -1.f : 0.f));
        logabs += logf(fabsf(pivot));
      }

      if (!doswap) {
        // ================= common path: no swap, stage from registers ======
        if (tid > k + 1 && tid < NF)
          s_tc[mp][tid] = make_float2(-vk * invp, vk1);
        __syncthreads();                                  // B2
      } else {
        const bool inpanel = (kp < pend);
        float gvr = 0.f;
        if (inpanel) {
          // ---- case B: in-panel swap ----
          const int lckp = kp - k0;
          if (tid > k + 1 && tid < NF && tid != kp) {
            float a = P[tid * PP + lc1], b2 = P[tid * PP + lckp];
            P[tid * PP + lc1] = b2; P[tid * PP + lckp] = a;
          } else if (tid >= NF && tid < NF + WP) {
            int c = tid - NF;
            if (c != lc1 && c != lckp) {
              float a = P[(k + 1) * PP + c], b2 = P[kp * PP + c];
              P[(k + 1) * PP + c] = b2; P[kp * PP + c] = a;
            }
          } else if (tid == NF + WP) {
            float a = P[kp * PP + lc1];         // old A[kp][k+1]
            float b2 = P[(k + 1) * PP + lckp];  // old A[k+1][kp]
            P[(k + 1) * PP + lc1] = 0.f;  P[(k + 1) * PP + lckp] = a;
            P[kp * PP + lc1] = b2;        P[kp * PP + lckp] = 0.f;
          } else if (tid >= NF + 24 && tid < NF + 24 + mp) {
            int m = tid - (NF + 24);
            float2 a = s_tc[m][k + 1], b2 = s_tc[m][kp];
            s_tc[m][k + 1] = b2; s_tc[m][kp] = a;
          }
        } else {
          // ---- case C: trailing swap, direct snapshot writeback (live region
          // only: rows/cols < pend other than row kp's panel cells are dead) --
          if (tid >= pend && tid < NF) {
            if (tid == kp) {
              A[(size_t)kp * NF + kp] = 0.f;
            } else {
              float pvv = P[tid * PP + lc1];
              gvr = A[(size_t)tid * NF + kp];
              A[(size_t)tid * NF + kp] = pvv;
              A[(size_t)kp * NF + tid] = -pvv;
            }
          } else if (tid >= NF && tid < NF + WP) {
            int c = tid - NF;
            float old = P[kp * PP + c];
            s_oldrow[c] = old;
            P[kp * PP + c] = P[(k + 1) * PP + c];
          } else if (tid >= NF + 24 && tid < NF + 24 + mp) {
            int m = tid - (NF + 24);
            float2 a = s_tc[m][k + 1], b2 = s_tc[m][kp];
            s_tc[m][k + 1] = b2; s_tc[m][kp] = a;
          }
        }
        __syncthreads();                                  // B2
        // ---- staging (post-swap; corrections use post-swap entries) ----
        if (tid > k + 1 && tid < NF) {
          float vpost = (tid == kp) ? s_colbuf[k + 1] : vk;
          float tt = -vpost * invp;
          float cc;
          if (inpanel)        cc = P[tid * PP + lc1];
          else if (tid < pend) cc = -s_oldrow[tid - k0];
          else if (tid == kp)  cc = -s_oldrow[lc1];
          else                 cc = gvr;
          for (int m = 0; m < mp; ++m) {
            float2 ti = s_tc[m][tid], tk1 = s_tc[m][k + 1];
            cc = fmaf(ti.x, tk1.y, fmaf(-ti.y, tk1.x, cc));
          }
          s_tc[mp][tid] = make_float2(tt, cc);
        }
        __syncthreads();                                  // B3
      }
    }

    // ---- panel-end: streaming rank-16 update of trailing block ----
    if (pend < NF) {
      const int ty = tid >> 6, tx = tid & 63;
      const int nch = (NF - pend) >> 2;
      for (int i = pend + ty; i < NF; i += 8) {
        float ti[PAIRS], ci[PAIRS];
#pragma unroll
        for (int m = 0; m < PAIRS; ++m) { float2 t = s_tc[m][i]; ti[m] = t.x; ci[m] = t.y; }
        for (int j4 = tx; j4 < nch; j4 += 64) {
          const int j = pend + (j4 << 2);
          float* ap = A + (size_t)i * NF + j;
          float4 a = *(float4*)ap;
#pragma unroll
          for (int m = 0; m < PAIRS; ++m) {
            float2 c0 = s_tc[m][j],     c1 = s_tc[m][j + 1];
            float2 c2 = s_tc[m][j + 2], c3 = s_tc[m][j + 3];
            a.x = fmaf(ti[m], c0.y, fmaf(-ci[m], c0.x, a.x));
            a.y = fmaf(ti[m], c1.y, fmaf(-ci[m], c1.x, a.y));
            a.z = fmaf(ti[m], c2.y, fmaf(-ci[m], c2.x, a.z));
            a.w = fmaf(ti[m], c3.y, fmaf(-ci[m], c3.x, a.w));
          }
          *(float4*)ap = a;
        }
      }
    }
    __syncthreads();
  }

  if (tid == 0) { out[b] = sign; out[NB + b] = logabs; }
}

extern "C" void kernel_launch(void* const* d_in, const int* in_sizes, int n_in,
                              void* d_out, int out_size, void* d_ws, size_t ws_size,
                              hipStream_t stream) {
  const float* U  = (const float*)d_in[0];
  const float* J  = (const float*)d_in[1];
  const int* idx  = (const int*)d_in[2];
  float* out = (float*)d_out;
  float* ws = (float*)d_ws;

  float* Ja  = ws;                          // 480*480
  float* Tmp = Ja + (size_t)NM * NM;        // 32*256*480
  float* Ff  = Tmp + (size_t)NB * NE * NM;  // 32*288*288

  build_ja_k<<<dim3(256), dim3(256), 0, stream>>>(J, Ja);
  gemm1_k<<<dim3(8, 4, NB), dim3(256), 0, stream>>>(U, idx, Ja, Tmp);
  gemm2_k<<<dim3(4, 4, NB), dim3(256), 0, stream>>>(U, idx, Tmp, Ff);
  fill_edges_k<<<dim3(NB), dim3(256), 0, stream>>>(U, idx, Ff);
  pfpanel_k<<<dim3(NB), dim3(512), 0, stream>>>(Ff, out);
}